// Round 8
// baseline (865.521 us; speedup 1.0000x reference)
//
#include <hip/hip_runtime.h>
#include <math.h>

#define N_ATOM 1536
#define NLAYER 3
#define NC     196608L          // 1536*128
#define ZSTRIDE 786432L         // 4*NC per layer; layout [layer][head][atom][kj]

// ============ batched-GEMM descriptor ============
// mode 0: A used as-is (optional ks); mode 1: rowLN(A) (ks=gamma); mode 2: sg*rowLN(A)+ad
struct GD { const float* A; const float* B; float* C; const float* ks; const float* bias;
            const float* sg; const float* ad; int act; int ldb; int ldc; int mode; };
struct GB { GD g[18]; };

// ============ mega-kernel params ============
struct MP {
  float *qbuf, *kbuf, *vbuf, *gbuf, *gobuf, *trbuf, *h1, *h2, *aa;
  const float *zbias, *amask;
  const float *sgA, *adA, *sgT, *adT, *gsg, *gog;
  const float *Wq, *bq, *Wk, *Wv, *Wgate, *trW1, *trW2, *Wo, *Wout, *Wtok;
  const int *tok;
  float *out;
  int *ctrs;
  int layer;
  int has_next;   // 1 => blocks 576.. run gemm64 for layer+1; else scatter
};

// ---------------- device-scope sync helpers (producer-consumer chaining) ----------------
__device__ __forceinline__ void sig_done(int* c) {
  __syncthreads();
  __threadfence();
  if (threadIdx.x == 0)
    __hip_atomic_fetch_add(c, 1, __ATOMIC_RELEASE, __HIP_MEMORY_SCOPE_AGENT);
}
__device__ __forceinline__ void wait_for(int* c, int tgt) {
  if (threadIdx.x == 0) {
    while (__hip_atomic_load(c, __ATOMIC_ACQUIRE, __HIP_MEMORY_SCOPE_AGENT) < tgt)
      __builtin_amdgcn_s_sleep(2);
  }
  __syncthreads();
  __threadfence();
}

// ---------------- fused embedder + tokidx + pl/pm (also zeroes sync counters) ----------------
__global__ __launch_bounds__(128) void embed_tok_kernel(
    const float* __restrict__ pos, const float* __restrict__ rmask,
    const float* __restrict__ elem, const float* __restrict__ charge,
    const float* __restrict__ chars, const float* __restrict__ uid,
    const float* __restrict__ Wf, const float* __restrict__ W_l, const float* __restrict__ W_m,
    const float* __restrict__ a2t, const float* __restrict__ tmask,
    float* __restrict__ cl, float* __restrict__ aa,
    float* __restrict__ pl, float* __restrict__ pm,
    int* __restrict__ tok, float* __restrict__ amask, int* __restrict__ ctrs)
{
  int l = blockIdx.x, c = threadIdx.x;
  if (l == 0 && c < 8) ctrs[c] = 0;
  __shared__ int sidx[6];
  __shared__ float crow[128];
  if (elem[(long)l * 128 + c] > 0.5f) sidx[0] = c;
  float v0 = chars[(long)l * 256 + c];
  if (v0 > 0.5f) sidx[1 + (c >> 6)] = c & 63;
  float v1 = chars[(long)l * 256 + 128 + c];
  if (v1 > 0.5f) sidx[3 + (c >> 6)] = c & 63;
  for (int j = c; j < 384; j += 128)
    if (a2t[(long)l * 384 + j] > 0.5f) sidx[5] = j;
  __syncthreads();
  float acc = pos[l * 3 + 0] * Wf[c]
            + pos[l * 3 + 1] * Wf[128 + c]
            + pos[l * 3 + 2] * Wf[256 + c]
            + rmask[l] * Wf[384 + c]
            + Wf[(4 + sidx[0]) * 128 + c]
            + charge[l] * Wf[132 * 128 + c]
            + Wf[(133 + sidx[1]) * 128 + c]
            + Wf[(197 + sidx[2]) * 128 + c]
            + Wf[(261 + sidx[3]) * 128 + c]
            + Wf[(325 + sidx[4]) * 128 + c]
            + uid[l] * Wf[389 * 128 + c];
  long gi = (long)l * 128 + c;
  cl[gi] = acc; aa[gi] = acc; crow[c] = fmaxf(acc, 0.f);
  __syncthreads();
  if (c < 32) {
    const float* W = (c < 16) ? W_l : W_m;
    int o = c & 15;
    float s = 0.f;
    for (int cc = 0; cc < 128; cc++) s = fmaf(crow[cc], W[cc * 16 + o], s);
    if (c < 16) pl[l * 16 + o] = s; else pm[l * 16 + o] = s;
  }
  if (c == 127) {
    int j = sidx[5];
    tok[l] = j; amask[l] = tmask[j];
  }
}

// ---------------- shared 64x64 GEMM tile body (round-0 proven BK=32 pipeline) ----------------
__device__ __forceinline__ void gemm64_body(float* sm, const GD d, int row0, int col0) {
  float* As = sm; float* Bs = sm + 2176;
  float* rmu = sm + 4352;
  float* rsd = sm + 4416;
  int tid = threadIdx.x;
  if (d.mode >= 1) {
    int r = tid >> 2, sgi = tid & 3;
    const float* Ar = d.A + (long)(row0 + r) * 128 + sgi * 32;
    float4 vv[8];
    float s1 = 0.f;
#pragma unroll
    for (int c4 = 0; c4 < 8; c4++) {
      vv[c4] = *(const float4*)(Ar + c4 * 4);
      s1 += vv[c4].x + vv[c4].y + vv[c4].z + vv[c4].w;
    }
    s1 += __shfl_xor(s1, 1); s1 += __shfl_xor(s1, 2);
    float mu = s1 * (1.f / 128.f);
    float s2 = 0.f;
#pragma unroll
    for (int c4 = 0; c4 < 8; c4++) {
      float dx = vv[c4].x - mu, dy = vv[c4].y - mu, dz = vv[c4].z - mu, dw = vv[c4].w - mu;
      s2 += dx * dx + dy * dy + dz * dz + dw * dw;
    }
    s2 += __shfl_xor(s2, 1); s2 += __shfl_xor(s2, 2);
    if (sgi == 0) {
      rmu[r] = mu;
      rsd[r] = rsqrtf(s2 * (1.f / 128.f) + 1e-5f);
    }
  }
  int tx = tid & 15, ty = tid >> 4;
  float acc[4][4] = {};
  for (int k0 = 0; k0 < 128; k0 += 32) {
    __syncthreads();
    { int r = tid >> 3, k4 = tid & 7;
#pragma unroll
      for (int half = 0; half < 2; half++) {
        int row = r + half * 32;
        long gro = (long)(row0 + row) * 128 + k0 + k4 * 4;
        float4 v = *(const float4*)(d.A + gro);
        float vals[4] = {v.x, v.y, v.z, v.w};
        if (d.mode >= 1) {
          float mu = rmu[row], sd = rsd[row];
          if (d.mode == 2) {
            float4 sg4 = *(const float4*)(d.sg + gro);
            float4 ad4 = *(const float4*)(d.ad + gro);
            vals[0] = fmaf(sg4.x, (vals[0] - mu) * sd, ad4.x);
            vals[1] = fmaf(sg4.y, (vals[1] - mu) * sd, ad4.y);
            vals[2] = fmaf(sg4.z, (vals[2] - mu) * sd, ad4.z);
            vals[3] = fmaf(sg4.w, (vals[3] - mu) * sd, ad4.w);
          } else {
#pragma unroll
            for (int cc = 0; cc < 4; cc++) vals[cc] = (vals[cc] - mu) * sd;
          }
        }
        if (d.ks) {
          const float* kp = d.ks + k0 + k4 * 4;
#pragma unroll
          for (int cc = 0; cc < 4; cc++) vals[cc] *= kp[cc];
        }
        As[(k4 * 4 + 0) * 68 + row] = vals[0]; As[(k4 * 4 + 1) * 68 + row] = vals[1];
        As[(k4 * 4 + 2) * 68 + row] = vals[2]; As[(k4 * 4 + 3) * 68 + row] = vals[3];
      } }
    { int kk = tid >> 4, n4 = tid & 15;
#pragma unroll
      for (int half = 0; half < 2; half++) {
        int k = kk + half * 16;
        *(float4*)&Bs[k * 68 + n4 * 4] = *(const float4*)(d.B + (long)(k0 + k) * d.ldb + col0 + n4 * 4);
      } }
    __syncthreads();
#pragma unroll
    for (int kk = 0; kk < 32; kk++) {
      float4 a = *(const float4*)&As[kk * 68 + ty * 4];
      float4 b = *(const float4*)&Bs[kk * 68 + tx * 4];
      float av[4] = {a.x, a.y, a.z, a.w}, bv[4] = {b.x, b.y, b.z, b.w};
#pragma unroll
      for (int i = 0; i < 4; i++)
#pragma unroll
        for (int j = 0; j < 4; j++) acc[i][j] = fmaf(av[i], bv[j], acc[i][j]);
    }
  }
  __syncthreads();
#pragma unroll
  for (int i = 0; i < 4; i++) {
    int row = row0 + ty * 4 + i;
#pragma unroll
    for (int j = 0; j < 4; j++) {
      int col = col0 + tx * 4 + j;
      float x = acc[i][j];
      if (d.bias) x += d.bias[col];
      if (d.act == 1) x = 1.f / (1.f + expf(-x));
      else if (d.act == 2) x = fmaxf(x, 0.f);
      d.C[(long)row * d.ldc + col] = x;
    }
  }
}

// ---------------- batched GEMM kernel (layer-0 QKVG/h1/h2) ----------------
__global__ __launch_bounds__(256) void gemm64(GB args)
{
  __shared__ __align__(16) float sm[4480];
  gemm64_body(sm, args.g[blockIdx.z], blockIdx.y * 64, blockIdx.x * 64);
}

// ---------------- merged zbias + pre18; GEMM tiles (long) FIRST ----------------
__global__ __launch_bounds__(256) void zpre_kernel(
    const float* __restrict__ pos, const float* __restrict__ uid,
    const float* __restrict__ Wro, const float* __restrict__ Winv, const float* __restrict__ Wval,
    const float* __restrict__ M1, const float* __restrict__ M2, const float* __restrict__ M3,
    const float* __restrict__ Lg, const float* __restrict__ Lb, const float* __restrict__ Wb,
    const float* __restrict__ pl, const float* __restrict__ pm, float* __restrict__ zb,
    GB ba)
{
  __shared__ __align__(16) float sm[4480];
  int bid = blockIdx.x, tid = threadIdx.x;
  if (bid < 864) {
    GD d = ba.g[bid / 48];
    int tt = bid % 48;
    gemm64_body(sm, d, (tt >> 1) * 64, (tt & 1) * 64);
    return;
  }
  int zbid = bid - 864;
  if (tid < 48)  sm[tid] = Wro[tid];
  if (tid < 16)  { sm[48 + tid] = Winv[tid]; sm[64 + tid] = Wval[tid]; }
  sm[80 + tid] = M1[tid]; sm[336 + tid] = M2[tid]; sm[592 + tid] = M3[tid];
  if (tid < 48)  { sm[848 + tid] = Lg[tid]; sm[896 + tid] = Lb[tid]; }
  if (tid < 192) sm[944 + tid] = Wb[tid];
  __syncthreads();
  const float* sWro = sm;      const float* sWinv = sm + 48;  const float* sWval = sm + 64;
  const float* sM1 = sm + 80;  const float* sM2 = sm + 336;   const float* sM3 = sm + 592;
  const float* sLg = sm + 848; const float* sLb = sm + 896;   const float* sWb = sm + 944;
  int b = zbid >> 4;
  int pc = (zbid & 15) * 256 + tid;
  int qi = pc >> 7, kj = pc & 127;
  int l = b * 32 + qi, m = b * 32 - 48 + kj;
  long base = (long)(b * 32 + qi) * 128 + kj;
  if (m < 0 || m >= N_ATOM) {
    for (int i = 0; i < NLAYER; i++)
      for (int h = 0; h < 4; h++) zb[i * ZSTRIDE + h * NC + base] = 0.f;
    return;
  }
  float dx = pos[m * 3 + 0] - pos[l * 3 + 0];
  float dy = pos[m * 3 + 1] - pos[l * 3 + 1];
  float dz = pos[m * 3 + 2] - pos[l * 3 + 2];
  float v = (uid[m] == uid[l]) ? 1.f : 0.f;
  float inv = 1.f / (1.f + dx * dx + dy * dy + dz * dz);
  float pv[16], ha[16], hb[16];
#pragma unroll
  for (int j = 0; j < 16; j++)
    pv[j] = v * (dx * sWro[j] + dy * sWro[16 + j] + dz * sWro[32 + j] + inv * sWinv[j] + sWval[j])
            + pl[l * 16 + j] + pm[m * 16 + j];
#pragma unroll
  for (int jo = 0; jo < 16; jo++) { float s = 0.f; for (int ji = 0; ji < 16; ji++) s = fmaf(fmaxf(pv[ji], 0.f), sM1[ji * 16 + jo], s); ha[jo] = s; }
#pragma unroll
  for (int jo = 0; jo < 16; jo++) { float s = 0.f; for (int ji = 0; ji < 16; ji++) s = fmaf(fmaxf(ha[ji], 0.f), sM2[ji * 16 + jo], s); hb[jo] = s; }
#pragma unroll
  for (int jo = 0; jo < 16; jo++) { float s = 0.f; for (int ji = 0; ji < 16; ji++) s = fmaf(fmaxf(hb[ji], 0.f), sM3[ji * 16 + jo], s); ha[jo] = s; }
#pragma unroll
  for (int j = 0; j < 16; j++) pv[j] += ha[j];
  for (int i = 0; i < NLAYER; i++) {
    float mu = 0.f;
#pragma unroll
    for (int j = 0; j < 16; j++) mu += pv[j];
    mu *= (1.f / 16.f);
    float var = 0.f;
#pragma unroll
    for (int j = 0; j < 16; j++) { float dd = pv[j] - mu; var += dd * dd; }
    var *= (1.f / 16.f);
    float rs = rsqrtf(var + 1e-5f);
    float zn[16];
#pragma unroll
    for (int j = 0; j < 16; j++) zn[j] = (pv[j] - mu) * rs * sLg[i * 16 + j] + sLb[i * 16 + j];
    for (int h = 0; h < 4; h++) {
      float s = 0.f;
#pragma unroll
      for (int j = 0; j < 16; j++) s = fmaf(zn[j], sWb[i * 64 + j * 4 + h], s);
      zb[i * ZSTRIDE + h * NC + base] = s;
    }
  }
}

// ---------------- phase bodies (verbatim R7 kernels, parameterized) ----------------
__device__ __forceinline__ GD make_gd(const MP& P, int i, int slot) {
  GD d;
  d.A = P.aa; d.ks = nullptr; d.bias = nullptr; d.act = 0; d.mode = 2;
  long o = (long)i * NC;
  if (slot < 4) { d.sg = P.sgA + o; d.ad = P.adA + o; d.ldb = 128; d.ldc = 128; }
  else          { d.sg = P.sgT + o; d.ad = P.adT + o; d.ldb = 256; d.ldc = 256; }
  switch (slot) {
    case 0: d.B = P.Wq + i * 16384;          d.C = P.qbuf;     d.bias = P.bq + i * 128; break;
    case 1: d.B = P.Wk + i * 16384;          d.C = P.kbuf;     break;
    case 2: d.B = P.Wv + i * 16384;          d.C = P.vbuf;     break;
    case 3: d.B = P.Wgate + i * 16384;       d.C = P.gbuf;     d.act = 1; break;
    case 4: d.B = P.trW1 + i * 32768;        d.C = P.h1;       break;
    case 5: d.B = P.trW1 + i * 32768 + 128;  d.C = P.h1 + 128; break;
    case 6: d.B = P.trW2 + i * 32768;        d.C = P.h2;       break;
    default:d.B = P.trW2 + i * 32768 + 128;  d.C = P.h2 + 128; break;
  }
  return d;
}

__device__ __forceinline__ void tr_body(float* sm, const MP& P, int layer, int u) {
  int t = threadIdx.x;
  int row0 = (u >> 1) * 32, col0 = (u & 1) * 64;
  const float* B2 = P.Wout + layer * 32768;
  const float* g2 = P.gog + (long)layer * NC;
  float* As = sm; float* Bs = sm + 1152;
  int tx = t & 15, ty = t >> 4;
  float acc2[2][4] = {};
  for (int k0 = 0; k0 < 256; k0 += 32) {
    __syncthreads();
    { int r = t >> 3, k4 = t & 7;
      long o = (long)(row0 + r) * 256 + k0 + k4 * 4;
      float4 x = *(const float4*)(P.h1 + o);
      float4 y = *(const float4*)(P.h2 + o);
      As[(k4 * 4 + 0) * 36 + r] = (x.x / (1.f + expf(-x.x))) * y.x;
      As[(k4 * 4 + 1) * 36 + r] = (x.y / (1.f + expf(-x.y))) * y.y;
      As[(k4 * 4 + 2) * 36 + r] = (x.z / (1.f + expf(-x.z))) * y.z;
      As[(k4 * 4 + 3) * 36 + r] = (x.w / (1.f + expf(-x.w))) * y.w;
    }
    for (int e = t; e < 512; e += 256) {
      int k = e >> 4, n4 = e & 15;
      *(float4*)&Bs[k * 68 + n4 * 4] = *(const float4*)(B2 + (long)(k0 + k) * 128 + col0 + n4 * 4);
    }
    __syncthreads();
#pragma unroll
    for (int kk = 0; kk < 32; kk++) {
      float a0 = As[kk * 36 + ty * 2], a1 = As[kk * 36 + ty * 2 + 1];
      float4 b = *(const float4*)&Bs[kk * 68 + tx * 4];
      float bv[4] = {b.x, b.y, b.z, b.w};
#pragma unroll
      for (int j = 0; j < 4; j++) {
        acc2[0][j] = fmaf(a0, bv[j], acc2[0][j]);
        acc2[1][j] = fmaf(a1, bv[j], acc2[1][j]);
      }
    }
  }
#pragma unroll
  for (int i = 0; i < 2; i++) {
    long o = (long)(row0 + ty * 2 + i) * 128 + col0 + tx * 4;
    float4 g4 = *(const float4*)(g2 + o);
    float4 r;
    r.x = g4.x * acc2[i][0]; r.y = g4.y * acc2[i][1];
    r.z = g4.z * acc2[i][2]; r.w = g4.w * acc2[i][3];
    *(float4*)(P.trbuf + o) = r;
  }
}

__device__ __forceinline__ void attn_body(float* sm, const MP& P, int layer, int u) {
  float* qs = sm;
  float* ks = sm + 576;
  float* vs = sm + 5184;
  float* ps = sm + 9792;
  int t = threadIdx.x;
  int h = u / 96, bx = u - h * 96;
  int b = bx >> 1, half = bx & 1;
  int q0 = b * 32 + half * 16;
  int kbase = b * 32 - 48;
  const float* zbh = P.zbias + (long)layer * ZSTRIDE + (long)h * NC;
  if (t < 128) {
    int qi = t >> 3, c4 = t & 7;
    *(float4*)&qs[qi * 36 + c4 * 4] = *(const float4*)(P.qbuf + (long)(q0 + qi) * 128 + h * 32 + c4 * 4);
  }
  for (int idx = t; idx < 128 * 8; idx += 256) {
    int kj = idx >> 3, c4 = idx & 7;
    int m = kbase + kj;
    float4 kv = make_float4(0.f, 0.f, 0.f, 0.f), vv = make_float4(0.f, 0.f, 0.f, 0.f);
    if (m >= 0 && m < N_ATOM) {
      kv = *(const float4*)(P.kbuf + (long)m * 128 + h * 32 + c4 * 4);
      vv = *(const float4*)(P.vbuf + (long)m * 128 + h * 32 + c4 * 4);
    }
    *(float4*)&ks[kj * 36 + c4 * 4] = kv;
    *(float4*)&vs[kj * 36 + c4 * 4] = vv;
  }
  __syncthreads();
  const float isq = 0.17677669529663687f;
  for (int p = t; p < 2048; p += 256) {
    int qi = p >> 7, kj = p & 127;
    int m = kbase + kj;
    float s = 0.f;
#pragma unroll
    for (int c4 = 0; c4 < 8; c4++) {
      float4 a = *(const float4*)&qs[qi * 36 + c4 * 4];
      float4 k4 = *(const float4*)&ks[kj * 36 + c4 * 4];
      s = fmaf(a.x, k4.x, s); s = fmaf(a.y, k4.y, s);
      s = fmaf(a.z, k4.z, s); s = fmaf(a.w, k4.w, s);
    }
    float logit;
    if (m >= 0 && m < N_ATOM) {
      logit = s * isq + zbh[(long)(q0 + qi) * 128 + kj] + (P.amask[m] - 1.f) * 1e9f;
    } else {
      logit = -1e9f;
    }
    ps[qi * 132 + kj] = logit;
  }
  __syncthreads();
  {
    int row = t >> 4, ln = t & 15;
    float mx = -1e30f;
    for (int kj = ln; kj < 128; kj += 16) mx = fmaxf(mx, ps[row * 132 + kj]);
#pragma unroll
    for (int o = 8; o > 0; o >>= 1) mx = fmaxf(mx, __shfl_xor(mx, o));
    float smv = 0.f;
    for (int kj = ln; kj < 128; kj += 16) { float e = expf(ps[row * 132 + kj] - mx); ps[row * 132 + kj] = e; smv += e; }
#pragma unroll
    for (int o = 8; o > 0; o >>= 1) smv += __shfl_xor(smv, o);
    float r = 1.f / smv;
    for (int kj = ln; kj < 128; kj += 16) ps[row * 132 + kj] *= r;
  }
  __syncthreads();
  {
    int qi = t >> 4, seg = (t >> 3) & 1, c4 = t & 7;
    float4 acc = make_float4(0.f, 0.f, 0.f, 0.f);
    int kj0 = seg * 64;
#pragma unroll 4
    for (int kj = kj0; kj < kj0 + 64; kj++) {
      float p = ps[qi * 132 + kj];
      float4 v = *(const float4*)&vs[kj * 36 + c4 * 4];
      acc.x = fmaf(p, v.x, acc.x); acc.y = fmaf(p, v.y, acc.y);
      acc.z = fmaf(p, v.z, acc.z); acc.w = fmaf(p, v.w, acc.w);
    }
    acc.x += __shfl_xor(acc.x, 8);
    acc.y += __shfl_xor(acc.y, 8);
    acc.z += __shfl_xor(acc.z, 8);
    acc.w += __shfl_xor(acc.w, 8);
    if (seg == 0) {
      long gi = (long)(q0 + qi) * 128 + h * 32 + c4 * 4;
      float4 g = *(const float4*)(P.gbuf + gi);
      acc.x *= g.x; acc.y *= g.y; acc.z *= g.z; acc.w *= g.w;
      *(float4*)(P.gobuf + gi) = acc;
    }
  }
}

__device__ __forceinline__ void wo_body(float* sm, const MP& P, int layer, int u) {
  int t = threadIdx.x;
  int row0 = (u >> 1) * 32, col0 = (u & 1) * 64;
  const float* B1 = P.Wo + layer * 16384;
  const float* g1 = P.gsg + (long)layer * NC;
  float* As = sm; float* Bs = sm + 1152;
  int tx = t & 15, ty = t >> 4;
  float acc1[2][4] = {};
  for (int k0 = 0; k0 < 128; k0 += 32) {
    __syncthreads();
    { int r = t >> 3, k4 = t & 7;
      float4 v = *(const float4*)(P.gobuf + (long)(row0 + r) * 128 + k0 + k4 * 4);
      As[(k4 * 4 + 0) * 36 + r] = v.x; As[(k4 * 4 + 1) * 36 + r] = v.y;
      As[(k4 * 4 + 2) * 36 + r] = v.z; As[(k4 * 4 + 3) * 36 + r] = v.w;
    }
    for (int e = t; e < 512; e += 256) {
      int k = e >> 4, n4 = e & 15;
      *(float4*)&Bs[k * 68 + n4 * 4] = *(const float4*)(B1 + (long)(k0 + k) * 128 + col0 + n4 * 4);
    }
    __syncthreads();
#pragma unroll
    for (int kk = 0; kk < 32; kk++) {
      float a0 = As[kk * 36 + ty * 2], a1 = As[kk * 36 + ty * 2 + 1];
      float4 b = *(const float4*)&Bs[kk * 68 + tx * 4];
      float bv[4] = {b.x, b.y, b.z, b.w};
#pragma unroll
      for (int j = 0; j < 4; j++) {
        acc1[0][j] = fmaf(a0, bv[j], acc1[0][j]);
        acc1[1][j] = fmaf(a1, bv[j], acc1[1][j]);
      }
    }
  }
#pragma unroll
  for (int i = 0; i < 2; i++) {
    long o = (long)(row0 + ty * 2 + i) * 128 + col0 + tx * 4;
    float4 ga = *(const float4*)(g1 + o);
    float4 tv = *(const float4*)(P.trbuf + o);
    float4 r;
    r.x = ga.x * acc1[i][0] + tv.x;
    r.y = ga.y * acc1[i][1] + tv.y;
    r.z = ga.z * acc1[i][2] + tv.z;
    r.w = ga.w * acc1[i][3] + tv.w;
    *(float4*)(P.aa + o) = r;
  }
}

__device__ __forceinline__ void scatter_body(float* sm, const MP& P, int u) {
  float* As = sm; float* Bs = sm + 2176;
  int tid = threadIdx.x;
  int row0 = (u / 6) * 64, col0 = (u % 6) * 64;
  int tx = tid & 15, ty = tid >> 4;
  float acc[4][4] = {};
  for (int k0 = 0; k0 < 128; k0 += 32) {
    __syncthreads();
    { int r = tid >> 3, k4 = tid & 7;
#pragma unroll
      for (int half = 0; half < 2; half++) {
        int row = r + half * 32;
        float4 v = *(const float4*)(P.aa + (long)(row0 + row) * 128 + k0 + k4 * 4);
        As[(k4 * 4 + 0) * 68 + row] = v.x; As[(k4 * 4 + 1) * 68 + row] = v.y;
        As[(k4 * 4 + 2) * 68 + row] = v.z; As[(k4 * 4 + 3) * 68 + row] = v.w;
      } }
    { int kk = tid >> 4, n4 = tid & 15;
#pragma unroll
      for (int half = 0; half < 2; half++) {
        int k = kk + half * 16;
        *(float4*)&Bs[k * 68 + n4 * 4] = *(const float4*)(P.Wtok + (long)(k0 + k) * 384 + col0 + n4 * 4);
      } }
    __syncthreads();
#pragma unroll
    for (int kk = 0; kk < 32; kk++) {
      float4 a = *(const float4*)&As[kk * 68 + ty * 4];
      float4 b = *(const float4*)&Bs[kk * 68 + tx * 4];
      float av[4] = {a.x, a.y, a.z, a.w}, bv[4] = {b.x, b.y, b.z, b.w};
#pragma unroll
      for (int i = 0; i < 4; i++)
#pragma unroll
        for (int j = 0; j < 4; j++) acc[i][j] = fmaf(av[i], bv[j], acc[i][j]);
    }
  }
  __syncthreads();
  int r0 = row0 + ty * 4;
  int t0 = P.tok[r0];
  int cnt = 0;
#pragma unroll
  for (int i = 0; i < 4; i++) cnt += (P.tok[r0 + i] == t0) ? 1 : 0;
  float inv = 1.f / fmaxf((float)cnt, 1.f);
#pragma unroll
  for (int j = 0; j < 4; j++) {
    int col = col0 + tx * 4 + j;
    float s = 0.f;
#pragma unroll
    for (int i = 0; i < 4; i++)
      if (P.tok[r0 + i] == t0) s += fmaxf(acc[i][j], 0.f);
    P.out[(long)t0 * 384 + col] = s * inv;
  }
}

// ---------------- mega: [tr(96) | attn(384)] -> wo(96) -> [gemm64(next,384) | scatter(144)] ----------------
// Deadlock-free: spinners (<=480) < co-residency slots (3 blocks/CU x 256 = 768).
__global__ __launch_bounds__(256) void mega_kernel(MP P)
{
  __shared__ __align__(16) float sm[11904];
  int bid = blockIdx.x;
  int i = P.layer;
  int* cA = P.ctrs + 2 * i;
  int* cB = cA + 1;
  if (bid < 96) {                       // transition GEMM (longest worker first)
    tr_body(sm, P, i, bid);
    sig_done(cA);
  } else if (bid < 480) {               // attention
    attn_body(sm, P, i, bid - 96);
    sig_done(cA);
  } else if (bid < 576) {               // wo: aa = gsg*(gobuf@Wo) + trbuf
    wait_for(cA, 480);
    wo_body(sm, P, i, bid - 480);
    sig_done(cB);
  } else if (P.has_next) {              // next layer's QKVG/h1/h2 GEMMs
    wait_for(cB, 96);
    int u = bid - 576;
    GD d = make_gd(P, i + 1, u / 48);
    int t48 = u % 48;
    gemm64_body(sm, d, (t48 >> 1) * 64, (t48 & 1) * 64);
  } else {                              // final token scatter
    wait_for(cB, 96);
    scatter_body(sm, P, bid - 576);
  }
}

extern "C" void kernel_launch(void* const* d_in, const int* in_sizes, int n_in,
                              void* d_out, int out_size, void* d_ws, size_t ws_size,
                              hipStream_t stream)
{
  const float* pos    = (const float*)d_in[0];
  const float* rmask  = (const float*)d_in[1];
  const float* elem   = (const float*)d_in[2];
  const float* charge = (const float*)d_in[3];
  const float* chars  = (const float*)d_in[4];
  const float* uid    = (const float*)d_in[5];
  const float* tmask  = (const float*)d_in[6];
  const float* a2t    = (const float*)d_in[7];
  const float* Wf     = (const float*)d_in[8];
  const float* Wro    = (const float*)d_in[9];
  const float* Winv   = (const float*)d_in[10];
  const float* Wval   = (const float*)d_in[11];
  const float* W_l    = (const float*)d_in[12];
  const float* W_m    = (const float*)d_in[13];
  const float* M1     = (const float*)d_in[14];
  const float* M2     = (const float*)d_in[15];
  const float* M3     = (const float*)d_in[16];
  const float* Wtok   = (const float*)d_in[17];
  const float* gA     = (const float*)d_in[18];
  const float* WgA    = (const float*)d_in[19];
  const float* bgA    = (const float*)d_in[20];
  const float* WsA    = (const float*)d_in[21];
  const float* Wq     = (const float*)d_in[22];
  const float* bq     = (const float*)d_in[23];
  const float* Wk     = (const float*)d_in[24];
  const float* Wv     = (const float*)d_in[25];
  const float* Lg     = (const float*)d_in[26];
  const float* Lb     = (const float*)d_in[27];
  const float* Wb     = (const float*)d_in[28];
  const float* Wgate  = (const float*)d_in[29];
  const float* Wo     = (const float*)d_in[30];
  const float* Wsg    = (const float*)d_in[31];
  const float* bsg    = (const float*)d_in[32];
  const float* gT     = (const float*)d_in[33];
  const float* WgT    = (const float*)d_in[34];
  const float* bgT    = (const float*)d_in[35];
  const float* WsT    = (const float*)d_in[36];
  const float* trW1   = (const float*)d_in[37];
  const float* trW2   = (const float*)d_in[38];
  const float* Wog    = (const float*)d_in[39];
  const float* bog    = (const float*)d_in[40];
  const float* Wout   = (const float*)d_in[41];
  float* out = (float*)d_out;

  float* ws = (float*)d_ws;
  size_t off = 0;
  auto alloc = [&](size_t n) { float* p = ws + off; off += n; return p; };
  float* cl     = alloc(NC);
  float* aa     = alloc(NC);
  float* qbuf   = alloc(NC);
  float* kbuf   = alloc(NC);
  float* vbuf   = alloc(NC);
  float* gbuf   = alloc(NC);
  float* gobuf  = alloc(NC);
  float* trbuf  = alloc(NC);
  float* h1     = alloc((size_t)N_ATOM * 256);
  float* h2     = alloc((size_t)N_ATOM * 256);
  float* pl     = alloc((size_t)N_ATOM * 16);
  float* pm     = alloc((size_t)N_ATOM * 16);
  float* zbias  = alloc((size_t)NLAYER * ZSTRIDE);
  float* sgA    = alloc(NC * NLAYER);
  float* adA    = alloc(NC * NLAYER);
  float* sgT    = alloc(NC * NLAYER);
  float* adT    = alloc(NC * NLAYER);
  float* gsg    = alloc(NC * NLAYER);
  float* gog    = alloc(NC * NLAYER);
  float* amask  = alloc(N_ATOM);
  int*   tok    = (int*)alloc(N_ATOM);
  int*   ctrs   = (int*)alloc(8);
  (void)ws_size; (void)in_sizes; (void)n_in; (void)out_size;

  embed_tok_kernel<<<N_ATOM, 128, 0, stream>>>(pos, rmask, elem, charge, chars, uid, Wf,
                                               W_l, W_m, a2t, tmask,
                                               cl, aa, pl, pm, tok, amask, ctrs);

  {
    GB ba = {};
    for (int i = 0; i < NLAYER; i++) {
      size_t o = (size_t)i * NC;
      ba.g[i * 6 + 0] = { cl, WgA + i * 16384, sgA + o, gA + i * 128, bgA + i * 128, nullptr, nullptr, 1, 128, 128, 1 };
      ba.g[i * 6 + 1] = { cl, WsA + i * 16384, adA + o, gA + i * 128, nullptr,       nullptr, nullptr, 0, 128, 128, 1 };
      ba.g[i * 6 + 2] = { cl, WgT + i * 16384, sgT + o, gT + i * 128, bgT + i * 128, nullptr, nullptr, 1, 128, 128, 1 };
      ba.g[i * 6 + 3] = { cl, WsT + i * 16384, adT + o, gT + i * 128, nullptr,       nullptr, nullptr, 0, 128, 128, 1 };
      ba.g[i * 6 + 4] = { cl, Wsg + i * 16384, gsg + o, nullptr,      bsg + i * 128, nullptr, nullptr, 1, 128, 128, 0 };
      ba.g[i * 6 + 5] = { cl, Wog + i * 16384, gog + o, nullptr,      bog + i * 128, nullptr, nullptr, 1, 128, 128, 0 };
    }
    zpre_kernel<<<768 + 864, 256, 0, stream>>>(pos, uid, Wro, Winv, Wval, M1, M2, M3,
                                               Lg, Lb, Wb, pl, pm, zbias, ba);
  }

  {
    // layer-0 QKVG/h1/h2 GEMMs (standalone; aa = embedding)
    GB ba = {};
    ba.g[0] = { aa, Wq,          qbuf,     nullptr, bq, sgA, adA, 0, 128, 128, 2 };
    ba.g[1] = { aa, Wk,          kbuf,     nullptr, nullptr, sgA, adA, 0, 128, 128, 2 };
    ba.g[2] = { aa, Wv,          vbuf,     nullptr, nullptr, sgA, adA, 0, 128, 128, 2 };
    ba.g[3] = { aa, Wgate,       gbuf,     nullptr, nullptr, sgA, adA, 1, 128, 128, 2 };
    ba.g[4] = { aa, trW1,        h1,       nullptr, nullptr, sgT, adT, 0, 256, 256, 2 };
    ba.g[5] = { aa, trW1 + 128,  h1 + 128, nullptr, nullptr, sgT, adT, 0, 256, 256, 2 };
    ba.g[6] = { aa, trW2,        h2,       nullptr, nullptr, sgT, adT, 0, 256, 256, 2 };
    ba.g[7] = { aa, trW2 + 128,  h2 + 128, nullptr, nullptr, sgT, adT, 0, 256, 256, 2 };
    gemm64<<<dim3(2, 24, 8), 256, 0, stream>>>(ba);
  }

  MP P;
  P.qbuf = qbuf; P.kbuf = kbuf; P.vbuf = vbuf; P.gbuf = gbuf;
  P.gobuf = gobuf; P.trbuf = trbuf; P.h1 = h1; P.h2 = h2; P.aa = aa;
  P.zbias = zbias; P.amask = amask;
  P.sgA = sgA; P.adA = adA; P.sgT = sgT; P.adT = adT; P.gsg = gsg; P.gog = gog;
  P.Wq = Wq; P.bq = bq; P.Wk = Wk; P.Wv = Wv; P.Wgate = Wgate;
  P.trW1 = trW1; P.trW2 = trW2; P.Wo = Wo; P.Wout = Wout; P.Wtok = Wtok;
  P.tok = tok; P.out = out; P.ctrs = ctrs;

  for (int i = 0; i < NLAYER; i++) {
    P.layer = i;
    P.has_next = (i < NLAYER - 1) ? 1 : 0;
    int nblocks = P.has_next ? 960 : 720;
    mega_kernel<<<nblocks, 256, 0, stream>>>(P);
  }
}

// Round 9
// 301.795 us; speedup vs baseline: 2.8679x; 2.8679x over previous
//
#include <hip/hip_runtime.h>
#include <math.h>

#define N_ATOM 1536
#define NLAYER 3
#define NC     196608L          // 1536*128
#define ZSTRIDE 786432L         // 4*NC per layer; layout [layer][head][atom][kj]

// ============ batched-GEMM descriptor ============
// mode 0: A used as-is (optional ks); mode 1: rowLN(A) (ks=gamma); mode 2: sg*rowLN(A)+ad
struct GD { const float* A; const float* B; float* C; const float* ks; const float* bias;
            const float* sg; const float* ad; int act; int ldb; int ldc; int mode; };
struct GB { GD g[18]; };

// ---------------- fused embedder + tokidx + pl/pm ----------------
__global__ __launch_bounds__(128) void embed_tok_kernel(
    const float* __restrict__ pos, const float* __restrict__ rmask,
    const float* __restrict__ elem, const float* __restrict__ charge,
    const float* __restrict__ chars, const float* __restrict__ uid,
    const float* __restrict__ Wf, const float* __restrict__ W_l, const float* __restrict__ W_m,
    const float* __restrict__ a2t, const float* __restrict__ tmask,
    float* __restrict__ cl, float* __restrict__ aa,
    float* __restrict__ pl, float* __restrict__ pm,
    int* __restrict__ tok, float* __restrict__ amask)
{
  int l = blockIdx.x, c = threadIdx.x;
  __shared__ int sidx[6];
  __shared__ float crow[128];
  if (elem[(long)l * 128 + c] > 0.5f) sidx[0] = c;
  float v0 = chars[(long)l * 256 + c];
  if (v0 > 0.5f) sidx[1 + (c >> 6)] = c & 63;
  float v1 = chars[(long)l * 256 + 128 + c];
  if (v1 > 0.5f) sidx[3 + (c >> 6)] = c & 63;
  for (int j = c; j < 384; j += 128)
    if (a2t[(long)l * 384 + j] > 0.5f) sidx[5] = j;
  __syncthreads();
  float acc = pos[l * 3 + 0] * Wf[c]
            + pos[l * 3 + 1] * Wf[128 + c]
            + pos[l * 3 + 2] * Wf[256 + c]
            + rmask[l] * Wf[384 + c]
            + Wf[(4 + sidx[0]) * 128 + c]
            + charge[l] * Wf[132 * 128 + c]
            + Wf[(133 + sidx[1]) * 128 + c]
            + Wf[(197 + sidx[2]) * 128 + c]
            + Wf[(261 + sidx[3]) * 128 + c]
            + Wf[(325 + sidx[4]) * 128 + c]
            + uid[l] * Wf[389 * 128 + c];
  long gi = (long)l * 128 + c;
  cl[gi] = acc; aa[gi] = acc; crow[c] = fmaxf(acc, 0.f);
  __syncthreads();
  if (c < 32) {
    const float* W = (c < 16) ? W_l : W_m;
    int o = c & 15;
    float s = 0.f;
    for (int cc = 0; cc < 128; cc++) s = fmaf(crow[cc], W[cc * 16 + o], s);
    if (c < 16) pl[l * 16 + o] = s; else pm[l * 16 + o] = s;
  }
  if (c == 127) {
    int j = sidx[5];
    tok[l] = j; amask[l] = tmask[j];
  }
}

// ---------------- 32x64 GEMM tile body (dual32-proven layout + mode LN logic) ----------------
// LDS: As[32*36] + Bs[32*68] + rmu[32] + rsd[32] = 3392 floats = 13.6 KB
__device__ __forceinline__ void gemm32_body(float* sm, const GD d, int row0, int col0) {
  float* As = sm;            // [k][row] transposed, stride 36
  float* Bs = sm + 1152;     // [k][col], stride 68
  float* rmu = sm + 3328;
  float* rsd = sm + 3360;
  int tid = threadIdx.x;
  if (d.mode >= 1) {
    // thread owns row (tid>>3), 16-float segment (tid&7); 8 owner lanes wave-consecutive
    int r = tid >> 3, sgi = tid & 7;
    const float* Ar = d.A + (long)(row0 + r) * 128 + sgi * 16;
    float4 vv[4];
    float s1 = 0.f;
#pragma unroll
    for (int c4 = 0; c4 < 4; c4++) {
      vv[c4] = *(const float4*)(Ar + c4 * 4);
      s1 += vv[c4].x + vv[c4].y + vv[c4].z + vv[c4].w;
    }
    s1 += __shfl_xor(s1, 1); s1 += __shfl_xor(s1, 2); s1 += __shfl_xor(s1, 4);
    float mu = s1 * (1.f / 128.f);
    float s2 = 0.f;
#pragma unroll
    for (int c4 = 0; c4 < 4; c4++) {
      float dx = vv[c4].x - mu, dy = vv[c4].y - mu, dz = vv[c4].z - mu, dw = vv[c4].w - mu;
      s2 += dx * dx + dy * dy + dz * dz + dw * dw;
    }
    s2 += __shfl_xor(s2, 1); s2 += __shfl_xor(s2, 2); s2 += __shfl_xor(s2, 4);
    if (sgi == 0) {
      rmu[r] = mu;
      rsd[r] = rsqrtf(s2 * (1.f / 128.f) + 1e-5f);
    }
  }
  int tx = tid & 15, ty = tid >> 4;
  float acc[2][4] = {};
  for (int k0 = 0; k0 < 128; k0 += 32) {
    __syncthreads();                      // iter 0 also publishes rmu/rsd
    { int r = tid >> 3, k4 = tid & 7;
      long gro = (long)(row0 + r) * 128 + k0 + k4 * 4;
      float4 v = *(const float4*)(d.A + gro);
      float vals[4] = {v.x, v.y, v.z, v.w};
      if (d.mode >= 1) {
        float mu = rmu[r], sd = rsd[r];
        if (d.mode == 2) {
          float4 sg4 = *(const float4*)(d.sg + gro);
          float4 ad4 = *(const float4*)(d.ad + gro);
          vals[0] = fmaf(sg4.x, (vals[0] - mu) * sd, ad4.x);
          vals[1] = fmaf(sg4.y, (vals[1] - mu) * sd, ad4.y);
          vals[2] = fmaf(sg4.z, (vals[2] - mu) * sd, ad4.z);
          vals[3] = fmaf(sg4.w, (vals[3] - mu) * sd, ad4.w);
        } else {
#pragma unroll
          for (int cc = 0; cc < 4; cc++) vals[cc] = (vals[cc] - mu) * sd;
        }
      }
      if (d.ks) {
        const float* kp = d.ks + k0 + k4 * 4;
#pragma unroll
        for (int cc = 0; cc < 4; cc++) vals[cc] *= kp[cc];
      }
      As[(k4 * 4 + 0) * 36 + r] = vals[0]; As[(k4 * 4 + 1) * 36 + r] = vals[1];
      As[(k4 * 4 + 2) * 36 + r] = vals[2]; As[(k4 * 4 + 3) * 36 + r] = vals[3];
    }
    for (int e = tid; e < 512; e += 256) {
      int k = e >> 4, n4 = e & 15;
      *(float4*)&Bs[k * 68 + n4 * 4] = *(const float4*)(d.B + (long)(k0 + k) * d.ldb + col0 + n4 * 4);
    }
    __syncthreads();
#pragma unroll
    for (int kk = 0; kk < 32; kk++) {
      float a0 = As[kk * 36 + ty * 2], a1 = As[kk * 36 + ty * 2 + 1];
      float4 b = *(const float4*)&Bs[kk * 68 + tx * 4];
      float bv[4] = {b.x, b.y, b.z, b.w};
#pragma unroll
      for (int j = 0; j < 4; j++) {
        acc[0][j] = fmaf(a0, bv[j], acc[0][j]);
        acc[1][j] = fmaf(a1, bv[j], acc[1][j]);
      }
    }
  }
#pragma unroll
  for (int i = 0; i < 2; i++) {
    int row = row0 + ty * 2 + i;
#pragma unroll
    for (int j = 0; j < 4; j++) {
      int col = col0 + tx * 4 + j;
      float x = acc[i][j];
      if (d.bias) x += d.bias[col];
      if (d.act == 1) x = 1.f / (1.f + expf(-x));
      else if (d.act == 2) x = fmaxf(x, 0.f);
      d.C[(long)row * d.ldc + col] = x;
    }
  }
}

// ---------------- batched GEMM kernel (32x64 tiles) ----------------
__global__ __launch_bounds__(256) void gemm32(GB args)
{
  __shared__ __align__(16) float sm[3392];
  gemm32_body(sm, args.g[blockIdx.z], blockIdx.y * 32, blockIdx.x * 64);
}

// ---------------- merged zbias + pre18; GEMM tiles (long) FIRST, 32x64 ----------------
__global__ __launch_bounds__(256) void zpre_kernel(
    const float* __restrict__ pos, const float* __restrict__ uid,
    const float* __restrict__ Wro, const float* __restrict__ Winv, const float* __restrict__ Wval,
    const float* __restrict__ M1, const float* __restrict__ M2, const float* __restrict__ M3,
    const float* __restrict__ Lg, const float* __restrict__ Lb, const float* __restrict__ Wb,
    const float* __restrict__ pl, const float* __restrict__ pm, float* __restrict__ zb,
    GB ba)
{
  __shared__ __align__(16) float sm[3392];
  int bid = blockIdx.x, tid = threadIdx.x;
  if (bid < 1728) {
    GD d = ba.g[bid / 96];
    int tt = bid % 96;
    gemm32_body(sm, d, (tt >> 1) * 32, (tt & 1) * 64);
    return;
  }
  int zbid = bid - 1728;
  if (tid < 48)  sm[tid] = Wro[tid];
  if (tid < 16)  { sm[48 + tid] = Winv[tid]; sm[64 + tid] = Wval[tid]; }
  sm[80 + tid] = M1[tid]; sm[336 + tid] = M2[tid]; sm[592 + tid] = M3[tid];
  if (tid < 48)  { sm[848 + tid] = Lg[tid]; sm[896 + tid] = Lb[tid]; }
  if (tid < 192) sm[944 + tid] = Wb[tid];
  __syncthreads();
  const float* sWro = sm;      const float* sWinv = sm + 48;  const float* sWval = sm + 64;
  const float* sM1 = sm + 80;  const float* sM2 = sm + 336;   const float* sM3 = sm + 592;
  const float* sLg = sm + 848; const float* sLb = sm + 896;   const float* sWb = sm + 944;
  int b = zbid >> 4;
  int pc = (zbid & 15) * 256 + tid;
  int qi = pc >> 7, kj = pc & 127;
  int l = b * 32 + qi, m = b * 32 - 48 + kj;
  long base = (long)(b * 32 + qi) * 128 + kj;
  if (m < 0 || m >= N_ATOM) {
    for (int i = 0; i < NLAYER; i++)
      for (int h = 0; h < 4; h++) zb[i * ZSTRIDE + h * NC + base] = 0.f;
    return;
  }
  float dx = pos[m * 3 + 0] - pos[l * 3 + 0];
  float dy = pos[m * 3 + 1] - pos[l * 3 + 1];
  float dz = pos[m * 3 + 2] - pos[l * 3 + 2];
  float v = (uid[m] == uid[l]) ? 1.f : 0.f;
  float inv = 1.f / (1.f + dx * dx + dy * dy + dz * dz);
  float pv[16], ha[16], hb[16];
#pragma unroll
  for (int j = 0; j < 16; j++)
    pv[j] = v * (dx * sWro[j] + dy * sWro[16 + j] + dz * sWro[32 + j] + inv * sWinv[j] + sWval[j])
            + pl[l * 16 + j] + pm[m * 16 + j];
#pragma unroll
  for (int jo = 0; jo < 16; jo++) { float s = 0.f; for (int ji = 0; ji < 16; ji++) s = fmaf(fmaxf(pv[ji], 0.f), sM1[ji * 16 + jo], s); ha[jo] = s; }
#pragma unroll
  for (int jo = 0; jo < 16; jo++) { float s = 0.f; for (int ji = 0; ji < 16; ji++) s = fmaf(fmaxf(ha[ji], 0.f), sM2[ji * 16 + jo], s); hb[jo] = s; }
#pragma unroll
  for (int jo = 0; jo < 16; jo++) { float s = 0.f; for (int ji = 0; ji < 16; ji++) s = fmaf(fmaxf(hb[ji], 0.f), sM3[ji * 16 + jo], s); ha[jo] = s; }
#pragma unroll
  for (int j = 0; j < 16; j++) pv[j] += ha[j];
  for (int i = 0; i < NLAYER; i++) {
    float mu = 0.f;
#pragma unroll
    for (int j = 0; j < 16; j++) mu += pv[j];
    mu *= (1.f / 16.f);
    float var = 0.f;
#pragma unroll
    for (int j = 0; j < 16; j++) { float dd = pv[j] - mu; var += dd * dd; }
    var *= (1.f / 16.f);
    float rs = rsqrtf(var + 1e-5f);
    float zn[16];
#pragma unroll
    for (int j = 0; j < 16; j++) zn[j] = (pv[j] - mu) * rs * sLg[i * 16 + j] + sLb[i * 16 + j];
    for (int h = 0; h < 4; h++) {
      float s = 0.f;
#pragma unroll
      for (int j = 0; j < 16; j++) s = fmaf(zn[j], sWb[i * 64 + j * 4 + h], s);
      zb[i * ZSTRIDE + h * NC + base] = s;
    }
  }
}

// ---------------- D2: transition GEMM (96, LONG, first) + attention (384) merged ----------------
__global__ __launch_bounds__(256) void attn_tr_kernel(
    const float* __restrict__ qb, const float* __restrict__ kb, const float* __restrict__ vb,
    const float* __restrict__ gb, const float* __restrict__ zb, const float* __restrict__ amask,
    float* __restrict__ go,
    const float* __restrict__ h1, const float* __restrict__ h2, const float* __restrict__ B2,
    const float* __restrict__ g2, float* __restrict__ trbuf)
{
  __shared__ __align__(16) float sm[11904];
  int bid = blockIdx.x, t = threadIdx.x;
  if (bid < 96) {
    // ---- transition GEMM tile (K=256, ~2x attn work) scheduled FIRST ----
    int u = bid;
    int row0 = (u >> 1) * 32, col0 = (u & 1) * 64;
    float* As = sm; float* Bs = sm + 1152;
    int tx = t & 15, ty = t >> 4;
    float acc2[2][4] = {};
    for (int k0 = 0; k0 < 256; k0 += 32) {
      __syncthreads();
      { int r = t >> 3, k4 = t & 7;
        long o = (long)(row0 + r) * 256 + k0 + k4 * 4;
        float4 x = *(const float4*)(h1 + o);
        float4 y = *(const float4*)(h2 + o);
        As[(k4 * 4 + 0) * 36 + r] = (x.x / (1.f + expf(-x.x))) * y.x;
        As[(k4 * 4 + 1) * 36 + r] = (x.y / (1.f + expf(-x.y))) * y.y;
        As[(k4 * 4 + 2) * 36 + r] = (x.z / (1.f + expf(-x.z))) * y.z;
        As[(k4 * 4 + 3) * 36 + r] = (x.w / (1.f + expf(-x.w))) * y.w;
      }
      for (int e = t; e < 512; e += 256) {
        int k = e >> 4, n4 = e & 15;
        *(float4*)&Bs[k * 68 + n4 * 4] = *(const float4*)(B2 + (long)(k0 + k) * 128 + col0 + n4 * 4);
      }
      __syncthreads();
#pragma unroll
      for (int kk = 0; kk < 32; kk++) {
        float a0 = As[kk * 36 + ty * 2], a1 = As[kk * 36 + ty * 2 + 1];
        float4 b = *(const float4*)&Bs[kk * 68 + tx * 4];
        float bv[4] = {b.x, b.y, b.z, b.w};
#pragma unroll
        for (int j = 0; j < 4; j++) {
          acc2[0][j] = fmaf(a0, bv[j], acc2[0][j]);
          acc2[1][j] = fmaf(a1, bv[j], acc2[1][j]);
        }
      }
    }
#pragma unroll
    for (int i = 0; i < 2; i++) {
      long o = (long)(row0 + ty * 2 + i) * 128 + col0 + tx * 4;
      float4 g4 = *(const float4*)(g2 + o);
      float4 r;
      r.x = g4.x * acc2[i][0]; r.y = g4.y * acc2[i][1];
      r.z = g4.z * acc2[i][2]; r.w = g4.w * acc2[i][3];
      *(float4*)(trbuf + o) = r;
    }
    return;
  }
  // ---- attention (blocks 96..479) ----
  float* qs = sm;                 // [16][36]
  float* ks = sm + 576;           // [128][36]
  float* vs = sm + 5184;          // [128][36]
  float* ps = sm + 9792;          // [16][132]
  int u = bid - 96;
  int h = u / 96, bx = u - h * 96;
  int b = bx >> 1, half = bx & 1;
  int q0 = b * 32 + half * 16;
  int kbase = b * 32 - 48;
  const float* zbh = zb + (long)h * NC;
  if (t < 128) {
    int qi = t >> 3, c4 = t & 7;
    *(float4*)&qs[qi * 36 + c4 * 4] = *(const float4*)(qb + (long)(q0 + qi) * 128 + h * 32 + c4 * 4);
  }
  for (int idx = t; idx < 128 * 8; idx += 256) {
    int kj = idx >> 3, c4 = idx & 7;
    int m = kbase + kj;
    float4 kv = make_float4(0.f, 0.f, 0.f, 0.f), vv = make_float4(0.f, 0.f, 0.f, 0.f);
    if (m >= 0 && m < N_ATOM) {
      kv = *(const float4*)(kb + (long)m * 128 + h * 32 + c4 * 4);
      vv = *(const float4*)(vb + (long)m * 128 + h * 32 + c4 * 4);
    }
    *(float4*)&ks[kj * 36 + c4 * 4] = kv;
    *(float4*)&vs[kj * 36 + c4 * 4] = vv;
  }
  __syncthreads();
  const float isq = 0.17677669529663687f;
  for (int p = t; p < 2048; p += 256) {
    int qi = p >> 7, kj = p & 127;
    int m = kbase + kj;
    float s = 0.f;
#pragma unroll
    for (int c4 = 0; c4 < 8; c4++) {
      float4 a = *(const float4*)&qs[qi * 36 + c4 * 4];
      float4 k4 = *(const float4*)&ks[kj * 36 + c4 * 4];
      s = fmaf(a.x, k4.x, s); s = fmaf(a.y, k4.y, s);
      s = fmaf(a.z, k4.z, s); s = fmaf(a.w, k4.w, s);
    }
    float logit;
    if (m >= 0 && m < N_ATOM) {
      logit = s * isq + zbh[(long)(q0 + qi) * 128 + kj] + (amask[m] - 1.f) * 1e9f;
    } else {
      logit = -1e9f;
    }
    ps[qi * 132 + kj] = logit;
  }
  __syncthreads();
  {
    int row = t >> 4, ln = t & 15;
    float mx = -1e30f;
    for (int kj = ln; kj < 128; kj += 16) mx = fmaxf(mx, ps[row * 132 + kj]);
#pragma unroll
    for (int o = 8; o > 0; o >>= 1) mx = fmaxf(mx, __shfl_xor(mx, o));
    float smv = 0.f;
    for (int kj = ln; kj < 128; kj += 16) { float e = expf(ps[row * 132 + kj] - mx); ps[row * 132 + kj] = e; smv += e; }
#pragma unroll
    for (int o = 8; o > 0; o >>= 1) smv += __shfl_xor(smv, o);
    float r = 1.f / smv;
    for (int kj = ln; kj < 128; kj += 16) ps[row * 132 + kj] *= r;
  }
  __syncthreads();
  {
    int qi = t >> 4, seg = (t >> 3) & 1, c4 = t & 7;
    float4 acc = make_float4(0.f, 0.f, 0.f, 0.f);
    int kj0 = seg * 64;
#pragma unroll 4
    for (int kj = kj0; kj < kj0 + 64; kj++) {
      float p = ps[qi * 132 + kj];
      float4 v = *(const float4*)&vs[kj * 36 + c4 * 4];
      acc.x = fmaf(p, v.x, acc.x); acc.y = fmaf(p, v.y, acc.y);
      acc.z = fmaf(p, v.z, acc.z); acc.w = fmaf(p, v.w, acc.w);
    }
    acc.x += __shfl_xor(acc.x, 8);
    acc.y += __shfl_xor(acc.y, 8);
    acc.z += __shfl_xor(acc.z, 8);
    acc.w += __shfl_xor(acc.w, 8);
    if (seg == 0) {
      long gi = (long)(q0 + qi) * 128 + h * 32 + c4 * 4;
      float4 g = *(const float4*)(gb + gi);
      acc.x *= g.x; acc.y *= g.y; acc.z *= g.z; acc.w *= g.w;
      *(float4*)(go + gi) = acc;
    }
  }
}

// ---------------- D3: aa = gsg*(gobuf @ Wo) + trbuf ; 32x64 tiles, K=128 ----------------
__global__ __launch_bounds__(256) void wo_kernel(
    const float* __restrict__ A1, const float* __restrict__ B1,
    const float* __restrict__ g1, const float* __restrict__ tr,
    float* __restrict__ C)
{
  __shared__ __align__(16) float As[32 * 36];
  __shared__ __align__(16) float Bs[32 * 68];
  const int N = 128;
  int t = threadIdx.x;
  int row0 = blockIdx.y * 32, col0 = blockIdx.x * 64;
  int tx = t & 15, ty = t >> 4;
  float acc1[2][4] = {};
  for (int k0 = 0; k0 < 128; k0 += 32) {
    __syncthreads();
    { int r = t >> 3, k4 = t & 7;
      float4 v = *(const float4*)(A1 + (long)(row0 + r) * 128 + k0 + k4 * 4);
      As[(k4 * 4 + 0) * 36 + r] = v.x; As[(k4 * 4 + 1) * 36 + r] = v.y;
      As[(k4 * 4 + 2) * 36 + r] = v.z; As[(k4 * 4 + 3) * 36 + r] = v.w;
    }
    for (int e = t; e < 512; e += 256) {
      int k = e >> 4, n4 = e & 15;
      *(float4*)&Bs[k * 68 + n4 * 4] = *(const float4*)(B1 + (long)(k0 + k) * N + col0 + n4 * 4);
    }
    __syncthreads();
#pragma unroll
    for (int kk = 0; kk < 32; kk++) {
      float a0 = As[kk * 36 + ty * 2], a1 = As[kk * 36 + ty * 2 + 1];
      float4 b = *(const float4*)&Bs[kk * 68 + tx * 4];
      float bv[4] = {b.x, b.y, b.z, b.w};
#pragma unroll
      for (int j = 0; j < 4; j++) {
        acc1[0][j] = fmaf(a0, bv[j], acc1[0][j]);
        acc1[1][j] = fmaf(a1, bv[j], acc1[1][j]);
      }
    }
  }
#pragma unroll
  for (int i = 0; i < 2; i++) {
    long o = (long)(row0 + ty * 2 + i) * N + col0 + tx * 4;
    float4 ga = *(const float4*)(g1 + o);
    float4 tv = *(const float4*)(tr + o);
    float4 r;
    r.x = ga.x * acc1[i][0] + tv.x;
    r.y = ga.y * acc1[i][1] + tv.y;
    r.z = ga.z * acc1[i][2] + tv.z;
    r.w = ga.w * acc1[i][3] + tv.w;
    *(float4*)(C + o) = r;
  }
}

// ------- final: out[t] = sum of its 4 atoms' relu(aa@Wtok)/cnt (direct write, no atomics) -------
__global__ __launch_bounds__(256) void gemm_scatter(
    const float* __restrict__ A, const float* __restrict__ B,
    const int* __restrict__ tok,
    float* __restrict__ out, int K)
{
  __shared__ __align__(16) float As[32][68];
  __shared__ __align__(16) float Bs[32][68];
  int tid = threadIdx.x;
  int row0 = blockIdx.y * 64, col0 = blockIdx.x * 64;
  int tx = tid & 15, ty = tid >> 4;
  float acc[4][4] = {};
  for (int k0 = 0; k0 < K; k0 += 32) {
    __syncthreads();
    { int r = tid >> 3, k4 = tid & 7;
#pragma unroll
      for (int half = 0; half < 2; half++) {
        int row = r + half * 32;
        float4 v = *(const float4*)(A + (long)(row0 + row) * K + k0 + k4 * 4);
        As[k4 * 4 + 0][row] = v.x; As[k4 * 4 + 1][row] = v.y;
        As[k4 * 4 + 2][row] = v.z; As[k4 * 4 + 3][row] = v.w;
      } }
    { int kk = tid >> 4, n4 = tid & 15;
#pragma unroll
      for (int half = 0; half < 2; half++) {
        int k = kk + half * 16;
        float4 v = *(const float4*)(B + (long)(k0 + k) * 384 + col0 + n4 * 4);
        *(float4*)&Bs[k][n4 * 4] = v;
      } }
    __syncthreads();
#pragma unroll
    for (int kk = 0; kk < 32; kk++) {
      float4 a = *(const float4*)&As[kk][ty * 4];
      float4 b = *(const float4*)&Bs[kk][tx * 4];
      float av[4] = {a.x, a.y, a.z, a.w}, bv[4] = {b.x, b.y, b.z, b.w};
#pragma unroll
      for (int i = 0; i < 4; i++)
#pragma unroll
        for (int j = 0; j < 4; j++) acc[i][j] = fmaf(av[i], bv[j], acc[i][j]);
    }
  }
  __syncthreads();
  int r0 = row0 + ty * 4;
  int t0 = tok[r0];
  int cnt = 0;
#pragma unroll
  for (int i = 0; i < 4; i++) cnt += (tok[r0 + i] == t0) ? 1 : 0;
  float inv = 1.f / fmaxf((float)cnt, 1.f);
#pragma unroll
  for (int j = 0; j < 4; j++) {
    int col = col0 + tx * 4 + j;
    float s = 0.f;
#pragma unroll
    for (int i = 0; i < 4; i++)
      if (tok[r0 + i] == t0) s += fmaxf(acc[i][j], 0.f);
    out[(long)t0 * 384 + col] = s * inv;
  }
}

extern "C" void kernel_launch(void* const* d_in, const int* in_sizes, int n_in,
                              void* d_out, int out_size, void* d_ws, size_t ws_size,
                              hipStream_t stream)
{
  const float* pos    = (const float*)d_in[0];
  const float* rmask  = (const float*)d_in[1];
  const float* elem   = (const float*)d_in[2];
  const float* charge = (const float*)d_in[3];
  const float* chars  = (const float*)d_in[4];
  const float* uid    = (const float*)d_in[5];
  const float* tmask  = (const float*)d_in[6];
  const float* a2t    = (const float*)d_in[7];
  const float* Wf     = (const float*)d_in[8];
  const float* Wro    = (const float*)d_in[9];
  const float* Winv   = (const float*)d_in[10];
  const float* Wval   = (const float*)d_in[11];
  const float* W_l    = (const float*)d_in[12];
  const float* W_m    = (const float*)d_in[13];
  const float* M1     = (const float*)d_in[14];
  const float* M2     = (const float*)d_in[15];
  const float* M3     = (const float*)d_in[16];
  const float* Wtok   = (const float*)d_in[17];
  const float* gA     = (const float*)d_in[18];
  const float* WgA    = (const float*)d_in[19];
  const float* bgA    = (const float*)d_in[20];
  const float* WsA    = (const float*)d_in[21];
  const float* Wq     = (const float*)d_in[22];
  const float* bq     = (const float*)d_in[23];
  const float* Wk     = (const float*)d_in[24];
  const float* Wv     = (const float*)d_in[25];
  const float* Lg     = (const float*)d_in[26];
  const float* Lb     = (const float*)d_in[27];
  const float* Wb     = (const float*)d_in[28];
  const float* Wgate  = (const float*)d_in[29];
  const float* Wo     = (const float*)d_in[30];
  const float* Wsg    = (const float*)d_in[31];
  const float* bsg    = (const float*)d_in[32];
  const float* gT     = (const float*)d_in[33];
  const float* WgT    = (const float*)d_in[34];
  const float* bgT    = (const float*)d_in[35];
  const float* WsT    = (const float*)d_in[36];
  const float* trW1   = (const float*)d_in[37];
  const float* trW2   = (const float*)d_in[38];
  const float* Wog    = (const float*)d_in[39];
  const float* bog    = (const float*)d_in[40];
  const float* Wout   = (const float*)d_in[41];
  float* out = (float*)d_out;

  float* ws = (float*)d_ws;
  size_t off = 0;
  auto alloc = [&](size_t n) { float* p = ws + off; off += n; return p; };
  float* cl     = alloc(NC);
  float* aa     = alloc(NC);
  float* qbuf   = alloc(NC);
  float* kbuf   = alloc(NC);
  float* vbuf   = alloc(NC);
  float* gbuf   = alloc(NC);
  float* gobuf  = alloc(NC);
  float* trbuf  = alloc(NC);
  float* h1     = alloc((size_t)N_ATOM * 256);
  float* h2     = alloc((size_t)N_ATOM * 256);
  float* pl     = alloc((size_t)N_ATOM * 16);
  float* pm     = alloc((size_t)N_ATOM * 16);
  float* zbias  = alloc((size_t)NLAYER * ZSTRIDE);
  float* sgA    = alloc(NC * NLAYER);
  float* adA    = alloc(NC * NLAYER);
  float* sgT    = alloc(NC * NLAYER);
  float* adT    = alloc(NC * NLAYER);
  float* gsg    = alloc(NC * NLAYER);
  float* gog    = alloc(NC * NLAYER);
  float* amask  = alloc(N_ATOM);
  int*   tok    = (int*)alloc(N_ATOM);
  (void)ws_size; (void)in_sizes; (void)n_in; (void)out_size;

  embed_tok_kernel<<<N_ATOM, 128, 0, stream>>>(pos, rmask, elem, charge, chars, uid, Wf,
                                               W_l, W_m, a2t, tmask,
                                               cl, aa, pl, pm, tok, amask);

  {
    GB ba = {};
    for (int i = 0; i < NLAYER; i++) {
      size_t o = (size_t)i * NC;
      ba.g[i * 6 + 0] = { cl, WgA + i * 16384, sgA + o, gA + i * 128, bgA + i * 128, nullptr, nullptr, 1, 128, 128, 1 };
      ba.g[i * 6 + 1] = { cl, WsA + i * 16384, adA + o, gA + i * 128, nullptr,       nullptr, nullptr, 0, 128, 128, 1 };
      ba.g[i * 6 + 2] = { cl, WgT + i * 16384, sgT + o, gT + i * 128, bgT + i * 128, nullptr, nullptr, 1, 128, 128, 1 };
      ba.g[i * 6 + 3] = { cl, WsT + i * 16384, adT + o, gT + i * 128, nullptr,       nullptr, nullptr, 0, 128, 128, 1 };
      ba.g[i * 6 + 4] = { cl, Wsg + i * 16384, gsg + o, nullptr,      bsg + i * 128, nullptr, nullptr, 1, 128, 128, 0 };
      ba.g[i * 6 + 5] = { cl, Wog + i * 16384, gog + o, nullptr,      bog + i * 128, nullptr, nullptr, 1, 128, 128, 0 };
    }
    zpre_kernel<<<1728 + 768, 256, 0, stream>>>(pos, uid, Wro, Winv, Wval, M1, M2, M3,
                                                Lg, Lb, Wb, pl, pm, zbias, ba);
  }

  for (int i = 0; i < NLAYER; i++) {
    size_t o = (size_t)i * NC;
    {
      // adaLN fused into A-staging: an/tn = sg*LN(aa)+ad computed in-block (mode 2)
      GB ba = {};
      ba.g[0] = { aa, Wq + i * 16384,        qbuf,     nullptr, bq + i * 128, sgA + o, adA + o, 0, 128, 128, 2 };
      ba.g[1] = { aa, Wk + i * 16384,        kbuf,     nullptr, nullptr,      sgA + o, adA + o, 0, 128, 128, 2 };
      ba.g[2] = { aa, Wv + i * 16384,        vbuf,     nullptr, nullptr,      sgA + o, adA + o, 0, 128, 128, 2 };
      ba.g[3] = { aa, Wgate + i * 16384,     gbuf,     nullptr, nullptr,      sgA + o, adA + o, 1, 128, 128, 2 };
      ba.g[4] = { aa, trW1 + i * 32768,       h1,      nullptr, nullptr,      sgT + o, adT + o, 0, 256, 256, 2 };
      ba.g[5] = { aa, trW1 + i * 32768 + 128, h1 + 128, nullptr, nullptr,     sgT + o, adT + o, 0, 256, 256, 2 };
      ba.g[6] = { aa, trW2 + i * 32768,       h2,      nullptr, nullptr,      sgT + o, adT + o, 0, 256, 256, 2 };
      ba.g[7] = { aa, trW2 + i * 32768 + 128, h2 + 128, nullptr, nullptr,     sgT + o, adT + o, 0, 256, 256, 2 };
      gemm32<<<dim3(2, 48, 8), 256, 0, stream>>>(ba);
    }
    attn_tr_kernel<<<480, 256, 0, stream>>>(qbuf, kbuf, vbuf, gbuf,
                                            zbias + (size_t)i * ZSTRIDE, amask, gobuf,
                                            h1, h2, Wout + i * 32768, gog + o, trbuf);
    wo_kernel<<<dim3(2, 48), 256, 0, stream>>>(gobuf, Wo + i * 16384, gsg + o, trbuf, aa);
  }

  gemm_scatter<<<dim3(6, 24), 256, 0, stream>>>(aa, Wtok, tok, out, 128);
}